// Round 12
// baseline (152.586 us; speedup 1.0000x reference)
//
#include <hip/hip_runtime.h>
#include <math.h>

#define BB    8
#define TDIM  64
#define NN    128
#define DD    128
#define TTOUT 62      // T-2
#define W3    384     // 3*N
#define LG    136     // ushort stride, 128-wide bf16 tiles (272B rows) — r9 proven
#define LP    40      // ushort stride, sFt/sP 32-wide tiles
#define LW    68      // ushort stride, FFN weight tiles (136B rows)

typedef __attribute__((ext_vector_type(8))) short bf16x8;
typedef __attribute__((ext_vector_type(4))) float f32x4;

__device__ __forceinline__ float sigf(float x){ return 1.0f/(1.0f+__expf(-x)); }
__device__ __forceinline__ unsigned short f2bf(float x){
  union{float f; unsigned u;} v; v.f=x;
  unsigned r = v.u + 0x7FFFu + ((v.u>>16)&1u);   // RNE
  return (unsigned short)(r>>16);
}

// K_pre: blocks 0..511: rscale + ssum (two coalesced passes).
//        blocks 512/513: W1/W2 -> transposed bf16.
__global__ __launch_bounds__(512) void k_pre(const float* __restrict__ feat,
    const float* __restrict__ w, const float* __restrict__ W1, const float* __restrict__ W2,
    float* __restrict__ rscale, float* __restrict__ ssum,
    unsigned short* __restrict__ W1T, unsigned short* __restrict__ W2T){
  __shared__ float sSig[DD];
  __shared__ float sRs[NN];
  __shared__ float sPart[4*DD];
  const int bid = blockIdx.x, tid = threadIdx.x;
  if(bid >= BB*TDIM){
    const float* W = (bid == BB*TDIM) ? W1 : W2;
    unsigned short* WT = (bid == BB*TDIM) ? W1T : W2T;
    for(int e=tid; e<DD*DD; e+=512){
      int k = e>>7, n = e&127;
      WT[n*DD + k] = f2bf(W[(size_t)k*DD + n]);
    }
    return;
  }
  const int bt = bid;
  if(tid < DD) sSig[tid] = sigf(w[tid]);
  __syncthreads();
  const int row = tid >> 2, q = tid & 3;
  const float* fp = feat + ((size_t)bt*NN + row)*DD + q*32;
  float ss = 0.f;
  #pragma unroll
  for(int i=0;i<8;i++){
    float4 v = *(const float4*)(fp + i*4);
    float g0 = v.x*sSig[q*32+i*4+0], g1 = v.y*sSig[q*32+i*4+1];
    float g2 = v.z*sSig[q*32+i*4+2], g3 = v.w*sSig[q*32+i*4+3];
    ss += g0*g0 + g1*g1 + g2*g2 + g3*g3;
  }
  ss += __shfl_xor(ss,1); ss += __shfl_xor(ss,2);
  float rs = 1.0f / fmaxf(sqrtf(ss), 1e-12f);
  if(q==0){ rscale[(size_t)bt*NN + row] = rs; sRs[row] = rs; }
  __syncthreads();
  const int d = tid & 127, rg = tid >> 7;
  const float* fc = feat + ((size_t)bt*NN + rg*32)*DD + d;
  float acc = 0.f;
  #pragma unroll 8
  for(int i=0;i<32;i++) acc += fc[(size_t)i*DD] * sRs[rg*32+i];
  sPart[rg*DD + d] = acc;
  __syncthreads();
  if(tid < DD)
    ssum[(size_t)bt*DD + tid] =
      (sPart[tid] + sPart[DD+tid] + sPart[2*DD+tid] + sPart[3*DD+tid]) * sSig[tid];
}

// K_dis: dis[b,tt,j] = deg>0 ? rsqrt(max(deg,1e-38)) : 0   (+ XCD swizzle)
__global__ void k_dis(const float* __restrict__ feat, const float* __restrict__ w,
                      const float* __restrict__ rscale, const float* __restrict__ ssum,
                      float* __restrict__ dis){
  __shared__ float s3[DD];
  __shared__ float sg[DD];
  int bt2 = (blockIdx.x & 7)*62 + (blockIdx.x >> 3);
  int b = bt2 / TTOUT, tt = bt2 % TTOUT;
  int tid = threadIdx.x;
  if(tid < DD){
    int base = (b*TDIM + tt)*DD;
    s3[tid] = ssum[base+tid] + ssum[base+DD+tid] + ssum[base+2*DD+tid];
    sg[tid] = sigf(w[tid]);
  }
  __syncthreads();
  int gr = (b*TDIM + tt)*NN + tid;
  const float4* fr = (const float4*)(feat + (size_t)gr*DD);
  float deg = 0.f;
  #pragma unroll 8
  for(int q=0;q<DD/4;q++){
    float4 f = fr[q];
    deg += f.x*sg[q*4+0]*s3[q*4+0] + f.y*sg[q*4+1]*s3[q*4+1]
         + f.z*sg[q*4+2]*s3[q*4+2] + f.w*sg[q*4+3]*s3[q*4+3];
  }
  deg *= rscale[gr];
  dis[(size_t)bt2*W3 + tid] = (deg > 0.f) ? rsqrtf(fmaxf(deg, 1e-38f)) : 0.f;
}

// K_main: r11 structure with the post-loop barrier fix (ovl aliases loop buffers,
// so all phase2 MFMA reads must complete before agg->ovl). LDS 52.7 KB => 3 blk/CU.
__global__ __launch_bounds__(512,6) void k_main(
    const float* __restrict__ feat,
    const float* __restrict__ w,
    const float* __restrict__ rscale, const float* __restrict__ dis,
    const unsigned short* __restrict__ W1T, const float* __restrict__ b1,
    const unsigned short* __restrict__ W2T, const float* __restrict__ b2,
    const float* __restrict__ gamma, const float* __restrict__ beta,
    float* __restrict__ out)
{
  // loop layout: sG @0 (32xLG), sFt @4352 (128xLP), sP @9472 (128xLP) -> 14592
  // FFN layout:  ovl @0 (128xLG = 17408), sWt @17408 (128xLW) -> 26112 (52,224B)
  __shared__ __align__(16) unsigned short sm[26112];
  __shared__ float sSig[DD];
  unsigned short* sG  = sm;
  unsigned short* sFt = sm + 4352;
  unsigned short* sP  = sm + 9472;
  unsigned short* ovl = sm;
  unsigned short* sWt = sm + 17408;

  const int tid = threadIdx.x;
  const int bid = blockIdx.x;
  const int bt2 = (bid & 7)*62 + (bid >> 3);   // XCD-chunked swizzle
  const int rowBase = (bt2/TTOUT)*TDIM*NN + (bt2%TTOUT)*NN;
  const float* disP = dis + (size_t)bt2*W3;

  const int lane = tid & 63, wid = tid >> 6;
  const int l15 = lane & 15, l4 = lane >> 4;
  const int m0 = wid * 16;

  if(tid < DD) sSig[tid] = sigf(w[tid]);
  __syncthreads();

  // A-fragments (scaled GhL rows 256..383, own M-strip) in registers: 16 VGPR/lane
  bf16x8 aReg[4];
  {
    const int j = 256 + m0 + l15, gr = rowBase + j;
    const float fac = rscale[gr]*disP[j];
    const float* fr = feat + (size_t)gr*DD;
    #pragma unroll
    for(int ks=0; ks<4; ++ks){
      float4 v0 = *(const float4*)(fr + ks*32 + l4*8);
      float4 v1 = *(const float4*)(fr + ks*32 + l4*8 + 4);
      const float* sg = sSig + ks*32 + l4*8;
      unsigned short o[8];
      o[0]=f2bf(v0.x*sg[0]*fac); o[1]=f2bf(v0.y*sg[1]*fac);
      o[2]=f2bf(v0.z*sg[2]*fac); o[3]=f2bf(v0.w*sg[3]*fac);
      o[4]=f2bf(v1.x*sg[4]*fac); o[5]=f2bf(v1.y*sg[5]*fac);
      o[6]=f2bf(v1.z*sg[6]*fac); o[7]=f2bf(v1.w*sg[7]*fac);
      aReg[ks] = *(bf16x8*)o;
    }
  }

  f32x4 acc2[8];
  #pragma unroll
  for(int i=0;i<8;i++) acc2[i] = (f32x4){0.f,0.f,0.f,0.f};

  for(int c=0; c<12; ++c){
    const int n0 = c*32;
    __syncthreads();   // prev phase2 done with sG/sFt/sP
    // stage sG (scaled bf16, row-major) + sFt (raw bf16, transposed [d][n])
    #pragma unroll
    for(int e0=0; e0<2; ++e0){
      int e = e0*512 + tid;
      int d = e & 127, r0 = (e>>7)*4;
      float sg = sSig[d];
      unsigned short fb[4];
      #pragma unroll
      for(int i=0;i<4;i++){
        int j = n0 + r0 + i, gr = rowBase + j;
        float f = feat[(size_t)gr*DD + d];
        float fac = rscale[gr]*disP[j];
        fb[i] = f2bf(f);
        sG[(r0+i)*LG + d] = f2bf(f*sg*fac);
      }
      unsigned int* fp = (unsigned int*)&sFt[d*LP + r0];
      fp[0] = (unsigned)fb[0] | ((unsigned)fb[1]<<16);
      fp[1] = (unsigned)fb[2] | ((unsigned)fb[3]<<16);
    }
    __syncthreads();

    // phase1: P[:, n0:n0+32] = Areg(16x128 per wave) x Gtile^T
    f32x4 p0 = {0.f,0.f,0.f,0.f}, p1 = {0.f,0.f,0.f,0.f};
    #pragma unroll
    for(int ks=0; ks<4; ++ks){
      bf16x8 bg0 = *(const bf16x8*)&sG[( 0+l15)*LG + ks*32 + l4*8];
      bf16x8 bg1 = *(const bf16x8*)&sG[(16+l15)*LG + ks*32 + l4*8];
      p0 = __builtin_amdgcn_mfma_f32_16x16x32_bf16(aReg[ks], bg0, p0, 0,0,0);
      p1 = __builtin_amdgcn_mfma_f32_16x16x32_bf16(aReg[ks], bg1, p1, 0,0,0);
    }
    #pragma unroll
    for(int r=0;r<4;r++){
      sP[(m0 + l4*4 + r)*LP +  0 + l15] = f2bf(p0[r]);
      sP[(m0 + l4*4 + r)*LP + 16 + l15] = f2bf(p1[r]);
    }
    __syncthreads();

    // phase2: agg += P(128x32) x F(32x128)
    bf16x8 aP = *(const bf16x8*)&sP[(m0+l15)*LP + l4*8];
    #pragma unroll
    for(int dt=0; dt<8; ++dt){
      bf16x8 bF = *(const bf16x8*)&sFt[(dt*16+l15)*LP + l4*8];
      acc2[dt] = __builtin_amdgcn_mfma_f32_16x16x32_bf16(aP, bF, acc2[dt], 0,0,0);
    }
  }

  __syncthreads();   // FIX: all waves' final phase2 reads done before ovl overwrite

  // agg -> ovl (bf16); wave-strip-local rows
  #pragma unroll
  for(int dt=0; dt<8; ++dt)
    #pragma unroll
    for(int r=0;r<4;r++)
      ovl[(m0+l4*4+r)*LG + dt*16+l15] = f2bf(acc2[dt][r]);

  // GEMM1: h = relu(agg @ W1 + b1)
  f32x4 acch[8];
  #pragma unroll
  for(int dt=0; dt<8; ++dt){
    float bv = b1[dt*16+l15];
    acch[dt] = (f32x4){bv,bv,bv,bv};
  }
  for(int kh=0; kh<2; ++kh){
    __syncthreads();
    #pragma unroll
    for(int it=0; it<2; ++it){
      int e = it*512 + tid, n = e>>3, sg2 = e&7;
      uint4 v = *(const uint4*)(W1T + (size_t)n*DD + kh*64 + sg2*8);
      *(uint4*)&sWt[n*LW + sg2*8] = v;
    }
    __syncthreads();
    #pragma unroll
    for(int ks=0; ks<2; ++ks){
      bf16x8 aA = *(const bf16x8*)&ovl[(m0+l15)*LG + kh*64 + ks*32 + l4*8];
      #pragma unroll
      for(int dt=0; dt<8; ++dt){
        bf16x8 bW = *(const bf16x8*)&sWt[(dt*16+l15)*LW + ks*32 + l4*8];
        acch[dt] = __builtin_amdgcn_mfma_f32_16x16x32_bf16(aA, bW, acch[dt], 0,0,0);
      }
    }
  }
  __syncthreads();
  // h -> ovl (strip-local)
  #pragma unroll
  for(int dt=0; dt<8; ++dt)
    #pragma unroll
    for(int r=0;r<4;r++)
      ovl[(m0+l4*4+r)*LG + dt*16+l15] = f2bf(fmaxf(acch[dt][r], 0.f));

  // GEMM2: o = h @ W2 + b2
  f32x4 acco[8];
  #pragma unroll
  for(int dt=0; dt<8; ++dt){
    float bv = b2[dt*16+l15];
    acco[dt] = (f32x4){bv,bv,bv,bv};
  }
  for(int kh=0; kh<2; ++kh){
    __syncthreads();
    #pragma unroll
    for(int it=0; it<2; ++it){
      int e = it*512 + tid, n = e>>3, sg2 = e&7;
      uint4 v = *(const uint4*)(W2T + (size_t)n*DD + kh*64 + sg2*8);
      *(uint4*)&sWt[n*LW + sg2*8] = v;
    }
    __syncthreads();
    #pragma unroll
    for(int ks=0; ks<2; ++ks){
      bf16x8 aA = *(const bf16x8*)&ovl[(m0+l15)*LG + kh*64 + ks*32 + l4*8];
      #pragma unroll
      for(int dt=0; dt<8; ++dt){
        bf16x8 bW = *(const bf16x8*)&sWt[(dt*16+l15)*LW + ks*32 + l4*8];
        acco[dt] = __builtin_amdgcn_mfma_f32_16x16x32_bf16(aA, bW, acco[dt], 0,0,0);
      }
    }
  }

  // residual + LayerNorm (fp32)
  const float* fres = feat + (size_t)(rowBase + 256)*DD;
  #pragma unroll
  for(int r=0;r<4;r++){
    int m = m0 + l4*4 + r;
    float vals[8]; float s1 = 0.f, s2 = 0.f;
    #pragma unroll
    for(int dt=0; dt<8; ++dt){
      int d = dt*16 + l15;
      float v = acco[dt][r] + fres[(size_t)m*DD + d];
      vals[dt] = v; s1 += v; s2 += v*v;
    }
    #pragma unroll
    for(int k=1;k<16;k<<=1){ s1 += __shfl_xor(s1,k); s2 += __shfl_xor(s2,k); }
    float mu   = s1*(1.0f/DD);
    float rstd = rsqrtf(s2*(1.0f/DD) - mu*mu + 1e-5f);
    #pragma unroll
    for(int dt=0; dt<8; ++dt){
      int d = dt*16 + l15;
      out[((size_t)bt2*NN + m)*DD + d] = (vals[dt]-mu)*rstd*gamma[d] + beta[d];
    }
  }
}

extern "C" void kernel_launch(void* const* d_in, const int* in_sizes, int n_in,
                              void* d_out, int out_size, void* d_ws, size_t ws_size,
                              hipStream_t stream){
  const float* feat  = (const float*)d_in[0];
  const float* w     = (const float*)d_in[1];
  const float* W1    = (const float*)d_in[2];
  const float* b1    = (const float*)d_in[3];
  const float* W2    = (const float*)d_in[4];
  const float* b2    = (const float*)d_in[5];
  const float* gamma = (const float*)d_in[6];
  const float* beta  = (const float*)d_in[7];
  float* out = (float*)d_out;

  char* ws = (char*)d_ws;
  float* rscale = (float*)(ws + 0);                       // 262,144 B
  float* ssum   = (float*)(ws + 262144);                  // 262,144 B
  float* dis    = (float*)(ws + 524288);                  // 761,856 B
  unsigned short* W1T = (unsigned short*)(ws + 1286144);  // 32,768 B
  unsigned short* W2T = (unsigned short*)(ws + 1318912);  // 32,768 B

  k_pre<<<BB*TDIM + 2, 512, 0, stream>>>(feat, w, W1, W2, rscale, ssum, W1T, W2T);
  k_dis<<<BB*TTOUT, W3, 0, stream>>>(feat, w, rscale, ssum, dis);
  k_main<<<BB*TTOUT, 512, 0, stream>>>(feat, w, rscale, dis, W1T, b1, W2T, b2,
                                       gamma, beta, out);
}

// Round 13
// 108.591 us; speedup vs baseline: 1.4051x; 1.4051x over previous
//
#include <hip/hip_runtime.h>
#include <math.h>

#define BB    8
#define TDIM  64
#define NN    128
#define DD    128
#define TTOUT 62      // T-2
#define W3    384     // 3*N
#define LG    136     // ushort stride, 128-wide bf16 tiles (272B rows) — r9 proven
#define LP    40      // ushort stride, sFt/sP 32-wide tiles
#define LW    68      // ushort stride, FFN weight tiles (136B rows)

typedef __attribute__((ext_vector_type(8))) short bf16x8;
typedef __attribute__((ext_vector_type(4))) float f32x4;

__device__ __forceinline__ float sigf(float x){ return 1.0f/(1.0f+__expf(-x)); }
__device__ __forceinline__ unsigned short f2bf(float x){
  union{float f; unsigned u;} v; v.f=x;
  unsigned r = v.u + 0x7FFFu + ((v.u>>16)&1u);   // RNE
  return (unsigned short)(r>>16);
}

// K_pre: blocks 0..511: rscale + ssum (two coalesced passes).
//        blocks 512/513: W1/W2 -> transposed bf16.
__global__ __launch_bounds__(512) void k_pre(const float* __restrict__ feat,
    const float* __restrict__ w, const float* __restrict__ W1, const float* __restrict__ W2,
    float* __restrict__ rscale, float* __restrict__ ssum,
    unsigned short* __restrict__ W1T, unsigned short* __restrict__ W2T){
  __shared__ float sSig[DD];
  __shared__ float sRs[NN];
  __shared__ float sPart[4*DD];
  const int bid = blockIdx.x, tid = threadIdx.x;
  if(bid >= BB*TDIM){
    const float* W = (bid == BB*TDIM) ? W1 : W2;
    unsigned short* WT = (bid == BB*TDIM) ? W1T : W2T;
    for(int e=tid; e<DD*DD; e+=512){
      int k = e>>7, n = e&127;
      WT[n*DD + k] = f2bf(W[(size_t)k*DD + n]);
    }
    return;
  }
  const int bt = bid;
  if(tid < DD) sSig[tid] = sigf(w[tid]);
  __syncthreads();
  const int row = tid >> 2, q = tid & 3;
  const float* fp = feat + ((size_t)bt*NN + row)*DD + q*32;
  float ss = 0.f;
  #pragma unroll
  for(int i=0;i<8;i++){
    float4 v = *(const float4*)(fp + i*4);
    float g0 = v.x*sSig[q*32+i*4+0], g1 = v.y*sSig[q*32+i*4+1];
    float g2 = v.z*sSig[q*32+i*4+2], g3 = v.w*sSig[q*32+i*4+3];
    ss += g0*g0 + g1*g1 + g2*g2 + g3*g3;
  }
  ss += __shfl_xor(ss,1); ss += __shfl_xor(ss,2);
  float rs = 1.0f / fmaxf(sqrtf(ss), 1e-12f);
  if(q==0){ rscale[(size_t)bt*NN + row] = rs; sRs[row] = rs; }
  __syncthreads();
  const int d = tid & 127, rg = tid >> 7;
  const float* fc = feat + ((size_t)bt*NN + rg*32)*DD + d;
  float acc = 0.f;
  #pragma unroll 8
  for(int i=0;i<32;i++) acc += fc[(size_t)i*DD] * sRs[rg*32+i];
  sPart[rg*DD + d] = acc;
  __syncthreads();
  if(tid < DD)
    ssum[(size_t)bt*DD + tid] =
      (sPart[tid] + sPart[DD+tid] + sPart[2*DD+tid] + sPart[3*DD+tid]) * sSig[tid];
}

// K_dis: dis[b,tt,j] = deg>0 ? rsqrt(max(deg,1e-38)) : 0   (+ XCD swizzle)
__global__ void k_dis(const float* __restrict__ feat, const float* __restrict__ w,
                      const float* __restrict__ rscale, const float* __restrict__ ssum,
                      float* __restrict__ dis){
  __shared__ float s3[DD];
  __shared__ float sg[DD];
  int bt2 = (blockIdx.x & 7)*62 + (blockIdx.x >> 3);
  int b = bt2 / TTOUT, tt = bt2 % TTOUT;
  int tid = threadIdx.x;
  if(tid < DD){
    int base = (b*TDIM + tt)*DD;
    s3[tid] = ssum[base+tid] + ssum[base+DD+tid] + ssum[base+2*DD+tid];
    sg[tid] = sigf(w[tid]);
  }
  __syncthreads();
  int gr = (b*TDIM + tt)*NN + tid;
  const float4* fr = (const float4*)(feat + (size_t)gr*DD);
  float deg = 0.f;
  #pragma unroll 8
  for(int q=0;q<DD/4;q++){
    float4 f = fr[q];
    deg += f.x*sg[q*4+0]*s3[q*4+0] + f.y*sg[q*4+1]*s3[q*4+1]
         + f.z*sg[q*4+2]*s3[q*4+2] + f.w*sg[q*4+3]*s3[q*4+3];
  }
  deg *= rscale[gr];
  dis[(size_t)bt2*W3 + tid] = (deg > 0.f) ? rsqrtf(fmaxf(deg, 1e-38f)) : 0.f;
}

// K_main: r12 structure verbatim; __launch_bounds__(512,3) -> VGPR cap ~85
// (no spill for aReg+acc2), LDS 52.7 KB -> 3 blocks/CU = 24 waves/CU.
__global__ __launch_bounds__(512,3) void k_main(
    const float* __restrict__ feat,
    const float* __restrict__ w,
    const float* __restrict__ rscale, const float* __restrict__ dis,
    const unsigned short* __restrict__ W1T, const float* __restrict__ b1,
    const unsigned short* __restrict__ W2T, const float* __restrict__ b2,
    const float* __restrict__ gamma, const float* __restrict__ beta,
    float* __restrict__ out)
{
  // loop layout: sG @0 (32xLG), sFt @4352 (128xLP), sP @9472 (128xLP) -> 14592
  // FFN layout:  ovl @0 (128xLG = 17408), sWt @17408 (128xLW) -> 26112 (52,224B)
  __shared__ __align__(16) unsigned short sm[26112];
  __shared__ float sSig[DD];
  unsigned short* sG  = sm;
  unsigned short* sFt = sm + 4352;
  unsigned short* sP  = sm + 9472;
  unsigned short* ovl = sm;
  unsigned short* sWt = sm + 17408;

  const int tid = threadIdx.x;
  const int bid = blockIdx.x;
  const int bt2 = (bid & 7)*62 + (bid >> 3);   // XCD-chunked swizzle
  const int rowBase = (bt2/TTOUT)*TDIM*NN + (bt2%TTOUT)*NN;
  const float* disP = dis + (size_t)bt2*W3;

  const int lane = tid & 63, wid = tid >> 6;
  const int l15 = lane & 15, l4 = lane >> 4;
  const int m0 = wid * 16;

  if(tid < DD) sSig[tid] = sigf(w[tid]);
  __syncthreads();

  // A-fragments (scaled GhL rows 256..383, own M-strip) in registers: 16 VGPR/lane
  bf16x8 aReg[4];
  {
    const int j = 256 + m0 + l15, gr = rowBase + j;
    const float fac = rscale[gr]*disP[j];
    const float* fr = feat + (size_t)gr*DD;
    #pragma unroll
    for(int ks=0; ks<4; ++ks){
      float4 v0 = *(const float4*)(fr + ks*32 + l4*8);
      float4 v1 = *(const float4*)(fr + ks*32 + l4*8 + 4);
      const float* sg = sSig + ks*32 + l4*8;
      unsigned short o[8];
      o[0]=f2bf(v0.x*sg[0]*fac); o[1]=f2bf(v0.y*sg[1]*fac);
      o[2]=f2bf(v0.z*sg[2]*fac); o[3]=f2bf(v0.w*sg[3]*fac);
      o[4]=f2bf(v1.x*sg[4]*fac); o[5]=f2bf(v1.y*sg[5]*fac);
      o[6]=f2bf(v1.z*sg[6]*fac); o[7]=f2bf(v1.w*sg[7]*fac);
      aReg[ks] = *(bf16x8*)o;
    }
  }

  f32x4 acc2[8];
  #pragma unroll
  for(int i=0;i<8;i++) acc2[i] = (f32x4){0.f,0.f,0.f,0.f};

  for(int c=0; c<12; ++c){
    const int n0 = c*32;
    __syncthreads();   // prev phase2 done with sG/sFt/sP
    // stage sG (scaled bf16, row-major) + sFt (raw bf16, transposed [d][n])
    #pragma unroll
    for(int e0=0; e0<2; ++e0){
      int e = e0*512 + tid;
      int d = e & 127, r0 = (e>>7)*4;
      float sg = sSig[d];
      unsigned short fb[4];
      #pragma unroll
      for(int i=0;i<4;i++){
        int j = n0 + r0 + i, gr = rowBase + j;
        float f = feat[(size_t)gr*DD + d];
        float fac = rscale[gr]*disP[j];
        fb[i] = f2bf(f);
        sG[(r0+i)*LG + d] = f2bf(f*sg*fac);
      }
      unsigned int* fp = (unsigned int*)&sFt[d*LP + r0];
      fp[0] = (unsigned)fb[0] | ((unsigned)fb[1]<<16);
      fp[1] = (unsigned)fb[2] | ((unsigned)fb[3]<<16);
    }
    __syncthreads();

    // phase1: P[:, n0:n0+32] = Areg(16x128 per wave) x Gtile^T
    f32x4 p0 = {0.f,0.f,0.f,0.f}, p1 = {0.f,0.f,0.f,0.f};
    #pragma unroll
    for(int ks=0; ks<4; ++ks){
      bf16x8 bg0 = *(const bf16x8*)&sG[( 0+l15)*LG + ks*32 + l4*8];
      bf16x8 bg1 = *(const bf16x8*)&sG[(16+l15)*LG + ks*32 + l4*8];
      p0 = __builtin_amdgcn_mfma_f32_16x16x32_bf16(aReg[ks], bg0, p0, 0,0,0);
      p1 = __builtin_amdgcn_mfma_f32_16x16x32_bf16(aReg[ks], bg1, p1, 0,0,0);
    }
    #pragma unroll
    for(int r=0;r<4;r++){
      sP[(m0 + l4*4 + r)*LP +  0 + l15] = f2bf(p0[r]);
      sP[(m0 + l4*4 + r)*LP + 16 + l15] = f2bf(p1[r]);
    }
    __syncthreads();

    // phase2: agg += P(128x32) x F(32x128)
    bf16x8 aP = *(const bf16x8*)&sP[(m0+l15)*LP + l4*8];
    #pragma unroll
    for(int dt=0; dt<8; ++dt){
      bf16x8 bF = *(const bf16x8*)&sFt[(dt*16+l15)*LP + l4*8];
      acc2[dt] = __builtin_amdgcn_mfma_f32_16x16x32_bf16(aP, bF, acc2[dt], 0,0,0);
    }
  }

  __syncthreads();   // all waves' final phase2 reads done before ovl overwrite

  // agg -> ovl (bf16); wave-strip-local rows
  #pragma unroll
  for(int dt=0; dt<8; ++dt)
    #pragma unroll
    for(int r=0;r<4;r++)
      ovl[(m0+l4*4+r)*LG + dt*16+l15] = f2bf(acc2[dt][r]);

  // GEMM1: h = relu(agg @ W1 + b1)
  f32x4 acch[8];
  #pragma unroll
  for(int dt=0; dt<8; ++dt){
    float bv = b1[dt*16+l15];
    acch[dt] = (f32x4){bv,bv,bv,bv};
  }
  for(int kh=0; kh<2; ++kh){
    __syncthreads();
    #pragma unroll
    for(int it=0; it<2; ++it){
      int e = it*512 + tid, n = e>>3, sg2 = e&7;
      uint4 v = *(const uint4*)(W1T + (size_t)n*DD + kh*64 + sg2*8);
      *(uint4*)&sWt[n*LW + sg2*8] = v;
    }
    __syncthreads();
    #pragma unroll
    for(int ks=0; ks<2; ++ks){
      bf16x8 aA = *(const bf16x8*)&ovl[(m0+l15)*LG + kh*64 + ks*32 + l4*8];
      #pragma unroll
      for(int dt=0; dt<8; ++dt){
        bf16x8 bW = *(const bf16x8*)&sWt[(dt*16+l15)*LW + ks*32 + l4*8];
        acch[dt] = __builtin_amdgcn_mfma_f32_16x16x32_bf16(aA, bW, acch[dt], 0,0,0);
      }
    }
  }
  __syncthreads();
  // h -> ovl (strip-local)
  #pragma unroll
  for(int dt=0; dt<8; ++dt)
    #pragma unroll
    for(int r=0;r<4;r++)
      ovl[(m0+l4*4+r)*LG + dt*16+l15] = f2bf(fmaxf(acch[dt][r], 0.f));

  // GEMM2: o = h @ W2 + b2
  f32x4 acco[8];
  #pragma unroll
  for(int dt=0; dt<8; ++dt){
    float bv = b2[dt*16+l15];
    acco[dt] = (f32x4){bv,bv,bv,bv};
  }
  for(int kh=0; kh<2; ++kh){
    __syncthreads();
    #pragma unroll
    for(int it=0; it<2; ++it){
      int e = it*512 + tid, n = e>>3, sg2 = e&7;
      uint4 v = *(const uint4*)(W2T + (size_t)n*DD + kh*64 + sg2*8);
      *(uint4*)&sWt[n*LW + sg2*8] = v;
    }
    __syncthreads();
    #pragma unroll
    for(int ks=0; ks<2; ++ks){
      bf16x8 aA = *(const bf16x8*)&ovl[(m0+l15)*LG + kh*64 + ks*32 + l4*8];
      #pragma unroll
      for(int dt=0; dt<8; ++dt){
        bf16x8 bW = *(const bf16x8*)&sWt[(dt*16+l15)*LW + ks*32 + l4*8];
        acco[dt] = __builtin_amdgcn_mfma_f32_16x16x32_bf16(aA, bW, acco[dt], 0,0,0);
      }
    }
  }

  // residual + LayerNorm (fp32)
  const float* fres = feat + (size_t)(rowBase + 256)*DD;
  #pragma unroll
  for(int r=0;r<4;r++){
    int m = m0 + l4*4 + r;
    float vals[8]; float s1 = 0.f, s2 = 0.f;
    #pragma unroll
    for(int dt=0; dt<8; ++dt){
      int d = dt*16 + l15;
      float v = acco[dt][r] + fres[(size_t)m*DD + d];
      vals[dt] = v; s1 += v; s2 += v*v;
    }
    #pragma unroll
    for(int k=1;k<16;k<<=1){ s1 += __shfl_xor(s1,k); s2 += __shfl_xor(s2,k); }
    float mu   = s1*(1.0f/DD);
    float rstd = rsqrtf(s2*(1.0f/DD) - mu*mu + 1e-5f);
    #pragma unroll
    for(int dt=0; dt<8; ++dt){
      int d = dt*16 + l15;
      out[((size_t)bt2*NN + m)*DD + d] = (vals[dt]-mu)*rstd*gamma[d] + beta[d];
    }
  }
}

extern "C" void kernel_launch(void* const* d_in, const int* in_sizes, int n_in,
                              void* d_out, int out_size, void* d_ws, size_t ws_size,
                              hipStream_t stream){
  const float* feat  = (const float*)d_in[0];
  const float* w     = (const float*)d_in[1];
  const float* W1    = (const float*)d_in[2];
  const float* b1    = (const float*)d_in[3];
  const float* W2    = (const float*)d_in[4];
  const float* b2    = (const float*)d_in[5];
  const float* gamma = (const float*)d_in[6];
  const float* beta  = (const float*)d_in[7];
  float* out = (float*)d_out;

  char* ws = (char*)d_ws;
  float* rscale = (float*)(ws + 0);                       // 262,144 B
  float* ssum   = (float*)(ws + 262144);                  // 262,144 B
  float* dis    = (float*)(ws + 524288);                  // 761,856 B
  unsigned short* W1T = (unsigned short*)(ws + 1286144);  // 32,768 B
  unsigned short* W2T = (unsigned short*)(ws + 1318912);  // 32,768 B

  k_pre<<<BB*TDIM + 2, 512, 0, stream>>>(feat, w, W1, W2, rscale, ssum, W1T, W2T);
  k_dis<<<BB*TTOUT, W3, 0, stream>>>(feat, w, rscale, ssum, dis);
  k_main<<<BB*TTOUT, 512, 0, stream>>>(feat, w, rscale, dis, W1T, b1, W2T, b2,
                                       gamma, beta, out);
}

// Round 14
// 81.361 us; speedup vs baseline: 1.8754x; 1.3347x over previous
//
#include <hip/hip_runtime.h>
#include <math.h>

#define BB    8
#define TDIM  64
#define NN    128
#define DD    128
#define TTOUT 62      // T-2
#define W3    384     // 3*N
#define LG    136     // ushort stride, 128-wide bf16 tiles (272B rows) — r9 proven
#define LP    40      // ushort stride, sFt/sP 32-wide tiles
#define LW    72      // ushort stride, FFN weight tiles (144B rows) — r9 value

typedef __attribute__((ext_vector_type(8))) short bf16x8;
typedef __attribute__((ext_vector_type(4))) float f32x4;

__device__ __forceinline__ float sigf(float x){ return 1.0f/(1.0f+__expf(-x)); }
__device__ __forceinline__ unsigned short f2bf(float x){
  union{float f; unsigned u;} v; v.f=x;
  unsigned r = v.u + 0x7FFFu + ((v.u>>16)&1u);   // RNE
  return (unsigned short)(r>>16);
}

// K_pre: blocks 0..511: rscale + ssum (two coalesced passes).
//        blocks 512/513: W1/W2 -> transposed bf16.   (r9 proven)
__global__ __launch_bounds__(512) void k_pre(const float* __restrict__ feat,
    const float* __restrict__ w, const float* __restrict__ W1, const float* __restrict__ W2,
    float* __restrict__ rscale, float* __restrict__ ssum,
    unsigned short* __restrict__ W1T, unsigned short* __restrict__ W2T){
  __shared__ float sSig[DD];
  __shared__ float sRs[NN];
  __shared__ float sPart[4*DD];
  const int bid = blockIdx.x, tid = threadIdx.x;
  if(bid >= BB*TDIM){
    const float* W = (bid == BB*TDIM) ? W1 : W2;
    unsigned short* WT = (bid == BB*TDIM) ? W1T : W2T;
    for(int e=tid; e<DD*DD; e+=512){
      int k = e>>7, n = e&127;
      WT[n*DD + k] = f2bf(W[(size_t)k*DD + n]);
    }
    return;
  }
  const int bt = bid;
  if(tid < DD) sSig[tid] = sigf(w[tid]);
  __syncthreads();
  const int row = tid >> 2, q = tid & 3;
  const float* fp = feat + ((size_t)bt*NN + row)*DD + q*32;
  float ss = 0.f;
  #pragma unroll
  for(int i=0;i<8;i++){
    float4 v = *(const float4*)(fp + i*4);
    float g0 = v.x*sSig[q*32+i*4+0], g1 = v.y*sSig[q*32+i*4+1];
    float g2 = v.z*sSig[q*32+i*4+2], g3 = v.w*sSig[q*32+i*4+3];
    ss += g0*g0 + g1*g1 + g2*g2 + g3*g3;
  }
  ss += __shfl_xor(ss,1); ss += __shfl_xor(ss,2);
  float rs = 1.0f / fmaxf(sqrtf(ss), 1e-12f);
  if(q==0){ rscale[(size_t)bt*NN + row] = rs; sRs[row] = rs; }
  __syncthreads();
  const int d = tid & 127, rg = tid >> 7;
  const float* fc = feat + ((size_t)bt*NN + rg*32)*DD + d;
  float acc = 0.f;
  #pragma unroll 8
  for(int i=0;i<32;i++) acc += fc[(size_t)i*DD] * sRs[rg*32+i];
  sPart[rg*DD + d] = acc;
  __syncthreads();
  if(tid < DD)
    ssum[(size_t)bt*DD + tid] =
      (sPart[tid] + sPart[DD+tid] + sPart[2*DD+tid] + sPart[3*DD+tid]) * sSig[tid];
}

// K_main: r9 core verbatim; dis computed in prologue (k_dis folded in);
// sFac (=dis*rscale) in LDS; phase1->phase2 barrier removed (wave-local sP).
__global__ __launch_bounds__(512,4) void k_main(
    const float* __restrict__ feat,
    const float* __restrict__ w,
    const float* __restrict__ rscale, const float* __restrict__ ssum,
    const unsigned short* __restrict__ W1T, const float* __restrict__ b1,
    const unsigned short* __restrict__ W2T, const float* __restrict__ b2,
    const float* __restrict__ gamma, const float* __restrict__ beta,
    float* __restrict__ out)
{
  __shared__ __align__(16) unsigned short sm[32000];   // 64 KB (r9 layout)
  __shared__ float sSig[DD];
  __shared__ float s3c[DD];
  __shared__ float sFac[W3];
  unsigned short* sA  = sm;            // 128 x LG : scaled GhL; later agg, then h
  unsigned short* sG  = sm + 17408;    // 32 x LG  : scaled window tile
  unsigned short* sFt = sm + 21760;    // 128 x LP : raw window tile, transposed [d][n]
  unsigned short* sP  = sm + 26880;    // 128 x LP : P chunk bf16
  unsigned short* sWt = sm + 17408;    // 128 x LW : FFN weights (overlays sG+sFt)

  const int tid = threadIdx.x;
  const int bid = blockIdx.x;
  const int bt2 = (bid & 7)*62 + (bid >> 3);   // XCD-chunked swizzle
  const int btIdx = (bt2/TTOUT)*TDIM + (bt2%TTOUT);
  const int rowBase = btIdx * NN;

  const int lane = tid & 63, wid = tid >> 6;
  const int l15 = lane & 15, l4 = lane >> 4;
  const int m0 = wid * 16;

  if(tid < DD){
    float sg = sigf(w[tid]);
    sSig[tid] = sg;
    float s3 = ssum[(size_t)btIdx*DD + tid] + ssum[(size_t)(btIdx+1)*DD + tid]
             + ssum[(size_t)(btIdx+2)*DD + tid];
    s3c[tid] = s3 * sg;
  }
  __syncthreads();

  // dis pass (was k_dis): deg = rs*(feat_row . s3c); sFac = dis*rs
  #pragma unroll
  for(int rg=0; rg<3; ++rg){
    int row = rg*128 + (tid>>2), q = tid&3;
    const float* fpr = feat + (size_t)(rowBase+row)*DD + q*32;
    float a = 0.f;
    #pragma unroll
    for(int i=0;i<8;i++){
      float4 v = *(const float4*)(fpr + i*4);
      const float* sc = s3c + q*32 + i*4;
      a += v.x*sc[0] + v.y*sc[1] + v.z*sc[2] + v.w*sc[3];
    }
    a += __shfl_xor(a,1); a += __shfl_xor(a,2);
    if(q==0){
      float rs = rscale[rowBase+row];
      float deg = a * rs;
      float dis = (deg > 0.f) ? rsqrtf(fmaxf(deg, 1e-38f)) : 0.f;
      sFac[row] = dis * rs;
    }
  }
  __syncthreads();

  // prologue: sA = scaled GhL (window rows 256..383) in bf16
  #pragma unroll
  for(int e0=0; e0<8; ++e0){
    int e = e0*512 + tid;
    int d = e & 127, r0 = (e>>7)*4;
    float sg = sSig[d];
    #pragma unroll
    for(int i=0;i<4;i++){
      int j = 256 + r0 + i;
      float f = feat[(size_t)(rowBase+j)*DD + d];
      sA[(r0+i)*LG + d] = f2bf(f*sg*sFac[j]);
    }
  }

  f32x4 acc2[8];
  #pragma unroll
  for(int i=0;i<8;i++) acc2[i] = (f32x4){0.f,0.f,0.f,0.f};

  for(int c=0; c<12; ++c){
    const int n0 = c*32;
    __syncthreads();   // prev phase2 done with sG/sFt (and prologue writes at c=0)
    // stage sG (scaled bf16, row-major) + sFt (raw bf16, transposed [d][n])
    #pragma unroll
    for(int e0=0; e0<2; ++e0){
      int e = e0*512 + tid;
      int d = e & 127, r0 = (e>>7)*4;
      float sg = sSig[d];
      unsigned short fb[4];
      #pragma unroll
      for(int i=0;i<4;i++){
        int j = n0 + r0 + i;
        float f = feat[(size_t)(rowBase+j)*DD + d];
        fb[i] = f2bf(f);
        sG[(r0+i)*LG + d] = f2bf(f*sg*sFac[j]);
      }
      unsigned int* fp = (unsigned int*)&sFt[d*LP + r0];
      fp[0] = (unsigned)fb[0] | ((unsigned)fb[1]<<16);
      fp[1] = (unsigned)fb[2] | ((unsigned)fb[3]<<16);
    }
    __syncthreads();

    // phase1: P[:, n0:n0+32] = GhL(128xK=128) x Gtile^T
    f32x4 p0 = {0.f,0.f,0.f,0.f}, p1 = {0.f,0.f,0.f,0.f};
    #pragma unroll
    for(int ks=0; ks<4; ++ks){
      bf16x8 aA  = *(const bf16x8*)&sA[(m0+l15)*LG + ks*32 + l4*8];
      bf16x8 bg0 = *(const bf16x8*)&sG[( 0+l15)*LG + ks*32 + l4*8];
      bf16x8 bg1 = *(const bf16x8*)&sG[(16+l15)*LG + ks*32 + l4*8];
      p0 = __builtin_amdgcn_mfma_f32_16x16x32_bf16(aA, bg0, p0, 0,0,0);
      p1 = __builtin_amdgcn_mfma_f32_16x16x32_bf16(aA, bg1, p1, 0,0,0);
    }
    #pragma unroll
    for(int r=0;r<4;r++){
      sP[(m0 + l4*4 + r)*LP +  0 + l15] = f2bf(p0[r]);
      sP[(m0 + l4*4 + r)*LP + 16 + l15] = f2bf(p1[r]);
    }
    // NO barrier: sP rows are wave-local (written & read by same wave's strip)

    // phase2: agg += P(128x32) x F(32x128)
    bf16x8 aP = *(const bf16x8*)&sP[(m0+l15)*LP + l4*8];
    #pragma unroll
    for(int dt=0; dt<8; ++dt){
      bf16x8 bF = *(const bf16x8*)&sFt[(dt*16+l15)*LP + l4*8];
      acc2[dt] = __builtin_amdgcn_mfma_f32_16x16x32_bf16(aP, bF, acc2[dt], 0,0,0);
    }
  }

  // agg -> sA (bf16); strip-local (safe: phase1 reads only own strip of sA)
  #pragma unroll
  for(int dt=0; dt<8; ++dt)
    #pragma unroll
    for(int r=0;r<4;r++)
      sA[(m0+l4*4+r)*LG + dt*16+l15] = f2bf(acc2[dt][r]);

  // GEMM1: h = relu(agg @ W1 + b1)
  f32x4 acch[8];
  #pragma unroll
  for(int dt=0; dt<8; ++dt){
    float bv = b1[dt*16+l15];
    acch[dt] = (f32x4){bv,bv,bv,bv};
  }
  for(int kh=0; kh<2; ++kh){
    __syncthreads();   // all waves past phase2 before sWt overwrites sG/sFt
    #pragma unroll
    for(int it=0; it<2; ++it){
      int e = it*512 + tid, n = e>>3, sg2 = e&7;
      uint4 v = *(const uint4*)(W1T + (size_t)n*DD + kh*64 + sg2*8);
      *(uint4*)&sWt[n*LW + sg2*8] = v;
    }
    __syncthreads();
    #pragma unroll
    for(int ks=0; ks<2; ++ks){
      bf16x8 aA = *(const bf16x8*)&sA[(m0+l15)*LG + kh*64 + ks*32 + l4*8];
      #pragma unroll
      for(int dt=0; dt<8; ++dt){
        bf16x8 bW = *(const bf16x8*)&sWt[(dt*16+l15)*LW + ks*32 + l4*8];
        acch[dt] = __builtin_amdgcn_mfma_f32_16x16x32_bf16(aA, bW, acch[dt], 0,0,0);
      }
    }
  }
  __syncthreads();
  // h -> sA (strip-local)
  #pragma unroll
  for(int dt=0; dt<8; ++dt)
    #pragma unroll
    for(int r=0;r<4;r++)
      sA[(m0+l4*4+r)*LG + dt*16+l15] = f2bf(fmaxf(acch[dt][r], 0.f));

  // GEMM2: o = h @ W2 + b2
  f32x4 acco[8];
  #pragma unroll
  for(int dt=0; dt<8; ++dt){
    float bv = b2[dt*16+l15];
    acco[dt] = (f32x4){bv,bv,bv,bv};
  }
  for(int kh=0; kh<2; ++kh){
    __syncthreads();
    #pragma unroll
    for(int it=0; it<2; ++it){
      int e = it*512 + tid, n = e>>3, sg2 = e&7;
      uint4 v = *(const uint4*)(W2T + (size_t)n*DD + kh*64 + sg2*8);
      *(uint4*)&sWt[n*LW + sg2*8] = v;
    }
    __syncthreads();
    #pragma unroll
    for(int ks=0; ks<2; ++ks){
      bf16x8 aA = *(const bf16x8*)&sA[(m0+l15)*LG + kh*64 + ks*32 + l4*8];
      #pragma unroll
      for(int dt=0; dt<8; ++dt){
        bf16x8 bW = *(const bf16x8*)&sWt[(dt*16+l15)*LW + ks*32 + l4*8];
        acco[dt] = __builtin_amdgcn_mfma_f32_16x16x32_bf16(aA, bW, acco[dt], 0,0,0);
      }
    }
  }

  // residual + LayerNorm (fp32)
  const float* fres = feat + (size_t)(rowBase + 256)*DD;
  #pragma unroll
  for(int r=0;r<4;r++){
    int m = m0 + l4*4 + r;
    float vals[8]; float s1 = 0.f, s2 = 0.f;
    #pragma unroll
    for(int dt=0; dt<8; ++dt){
      int d = dt*16 + l15;
      float v = acco[dt][r] + fres[(size_t)m*DD + d];
      vals[dt] = v; s1 += v; s2 += v*v;
    }
    #pragma unroll
    for(int k=1;k<16;k<<=1){ s1 += __shfl_xor(s1,k); s2 += __shfl_xor(s2,k); }
    float mu   = s1*(1.0f/DD);
    float rstd = rsqrtf(s2*(1.0f/DD) - mu*mu + 1e-5f);
    #pragma unroll
    for(int dt=0; dt<8; ++dt){
      int d = dt*16 + l15;
      out[((size_t)bt2*NN + m)*DD + d] = (vals[dt]-mu)*rstd*gamma[d] + beta[d];
    }
  }
}

extern "C" void kernel_launch(void* const* d_in, const int* in_sizes, int n_in,
                              void* d_out, int out_size, void* d_ws, size_t ws_size,
                              hipStream_t stream){
  const float* feat  = (const float*)d_in[0];
  const float* w     = (const float*)d_in[1];
  const float* W1    = (const float*)d_in[2];
  const float* b1    = (const float*)d_in[3];
  const float* W2    = (const float*)d_in[4];
  const float* b2    = (const float*)d_in[5];
  const float* gamma = (const float*)d_in[6];
  const float* beta  = (const float*)d_in[7];
  float* out = (float*)d_out;

  char* ws = (char*)d_ws;
  float* rscale = (float*)(ws + 0);                       // 262,144 B
  float* ssum   = (float*)(ws + 262144);                  // 262,144 B
  unsigned short* W1T = (unsigned short*)(ws + 524288);   // 32,768 B
  unsigned short* W2T = (unsigned short*)(ws + 557056);   // 32,768 B

  k_pre<<<BB*TDIM + 2, 512, 0, stream>>>(feat, w, W1, W2, rscale, ssum, W1T, W2T);
  k_main<<<BB*TTOUT, 512, 0, stream>>>(feat, w, rscale, ssum, W1T, b1, W2T, b2,
                                       gamma, beta, out);
}